// Round 7
// baseline (190.670 us; speedup 1.0000x reference)
//
#include <hip/hip_runtime.h>
#include <math.h>

#define BATCH 8
#define CIN 64
#define COUT 64
#define HH 128
#define WW 128
#define HW (HH*WW)
#define TPX 64       // pixels per block (half row)
#define KDIM 576     // K index = kf*64 + c

typedef __attribute__((ext_vector_type(8))) short short8;
typedef __attribute__((ext_vector_type(4))) float f32x4;

__device__ __forceinline__ unsigned short f2bf(float f) {
    union { float f; unsigned int u; } v; v.f = f;
    unsigned int u = v.u;
    u += 0x7FFFu + ((u >> 16) & 1u);   // RNE
    return (unsigned short)(u >> 16);
}
__device__ __forceinline__ float bf2f_s(short s) {
    union { unsigned int u; float f; } v;
    v.u = ((unsigned int)(unsigned short)s) << 16;
    return v.f;
}
__device__ __forceinline__ unsigned int cvt_pk_bf16(float lo, float hi) {
    unsigned int r;
    asm("v_cvt_pk_bf16_f32 %0, %1, %2" : "=v"(r) : "v"(lo), "v"(hi));
    return r;
}

// ---------------- Kernel 1: x[b][c][h][w] fp32 -> xT[b][h][w][c] bf16 ----------------
__global__ void __launch_bounds__(256) xpose_kernel(const float* __restrict__ x,
                                                    unsigned short* __restrict__ xT) {
    int idx = blockIdx.x * 256 + threadIdx.x;   // 1,048,576 total
    int c8 = idx & 7;
    int w  = (idx >> 3) & 127;
    int h  = (idx >> 10) & 127;
    int b  = idx >> 17;
    const float* xp = x + (((size_t)(b * 64 + c8 * 8) * 128 + h) * 128 + w);
    short8 o;
    unsigned int* ou = (unsigned int*)&o;
#pragma unroll
    for (int j = 0; j < 4; ++j)
        ou[j] = cvt_pk_bf16(xp[(size_t)(2 * j) * HW], xp[(size_t)(2 * j + 1) * HW]);
    *(short8*)(xT + (size_t)idx * 8) = o;
}

// ---------------- Kernel 2: weight casts/reorders to [o][kf*64+c] bf16 ----------------
__global__ void __launch_bounds__(256) wcast_kernel(const float* __restrict__ w_dcn,
                                                    const float* __restrict__ w_off,
                                                    unsigned short* __restrict__ wt,
                                                    unsigned short* __restrict__ wtoff) {
    int i = blockIdx.x * 256 + threadIdx.x;
    if (i < COUT * KDIM) {
        int o = i / KDIM, k = i % KDIM;
        int kf = k >> 6, c = k & 63;
        wt[i] = f2bf(w_dcn[(o * 64 + c) * 9 + kf]);
    } else {
        int i2 = i - COUT * KDIM;
        if (i2 < 32 * KDIM) {
            int o = i2 / KDIM, k = i2 % KDIM;
            int kf = k >> 6, c = k & 63;
            wtoff[i2] = (o < 27) ? f2bf(w_off[(o * 64 + c) * 9 + kf]) : (unsigned short)0;
        }
    }
}

// ---------------- Kernel 3: fused, register-resident gather -> MFMA ----------------
// Block = 64 px (half row). Wave wv owns px 16wv..16wv+15, ALL 64 outputs.
// Lane (l15,g4) gathers its own B-fragment; no LDS staging, 1 barrier total.
__global__ void __launch_bounds__(256, 4) fused_dcn_kernel(
        const unsigned short* __restrict__ xT,
        const unsigned short* __restrict__ wtoff,
        const float* __restrict__ b_off,
        const unsigned short* __restrict__ wt,
        float* __restrict__ out) {
    __shared__ float s_om[TPX * 29];            // 7424 B, stride 29 (odd -> bank-clean)

    int t = threadIdx.x;
    int blk0 = blockIdx.x;
    int blk = (blk0 & 7) * 256 + (blk0 >> 3);   // XCD swizzle (2048 = 8*256, bijective)
    int b = blk >> 8;
    int rem = blk & 255;
    int h = rem >> 1;
    int w0 = (rem & 1) << 6;

    int lane = t & 63;
    int wv = t >> 6;
    int l15 = lane & 15;
    int g4 = lane >> 4;
    int pxl = wv * 16 + l15;                    // local pixel 0..63
    int wg = w0 + pxl;                          // global col

    const unsigned short* xTb = xT + (size_t)b * HW * 64;

    // ---- phase A: offset conv (27ch) via MFMA; wave computes om for its own px ----
    {
        f32x4 ca0 = {0.f, 0.f, 0.f, 0.f};
        f32x4 ca1 = {0.f, 0.f, 0.f, 0.f};
        const unsigned short* ar0 = wtoff + (size_t)l15 * KDIM;
        const unsigned short* ar1 = wtoff + (size_t)(16 + l15) * KDIM;
#pragma unroll
        for (int kk = 0; kk < 18; ++kk) {
            int kf = kk >> 1;
            int ky = kf / 3, kx = kf % 3;
            int cb = (kk & 1) * 32 + g4 * 8;
            int row = h - 1 + ky;
            int col = wg - 1 + kx;
            short8 bfrag = {0, 0, 0, 0, 0, 0, 0, 0};
            if ((unsigned)row < 128u && (unsigned)col < 128u)
                bfrag = *(const short8*)(xTb + ((size_t)row * 128 + (size_t)col) * 64 + cb);
            short8 a0 = *(const short8*)(ar0 + kk * 32 + g4 * 8);
            short8 a1 = *(const short8*)(ar1 + kk * 32 + g4 * 8);
            ca0 = __builtin_amdgcn_mfma_f32_16x16x32_bf16(a0, bfrag, ca0, 0, 0, 0);
            ca1 = __builtin_amdgcn_mfma_f32_16x16x32_bf16(a1, bfrag, ca1, 0, 0, 0);
        }
        int ch0 = g4 * 4;
#pragma unroll
        for (int r = 0; r < 4; ++r) {
            s_om[pxl * 29 + ch0 + r] = ca0[r] + b_off[ch0 + r];
            if (ch0 + 16 + r < 27)
                s_om[pxl * 29 + 16 + ch0 + r] = ca1[r] + b_off[16 + ch0 + r];
        }
    }
    __syncthreads();

    // ---- main loop: per (kf, K-half): gather own B-fragment in regs, 4 MFMAs ----
    f32x4 acc0 = {0.f, 0.f, 0.f, 0.f};
    f32x4 acc1 = {0.f, 0.f, 0.f, 0.f};
    f32x4 acc2 = {0.f, 0.f, 0.f, 0.f};
    f32x4 acc3 = {0.f, 0.f, 0.f, 0.f};
    const unsigned short* wbase = wt + (size_t)l15 * KDIM + g4 * 8;
    const float* omb = s_om + pxl * 29;

#pragma unroll
    for (int kf = 0; kf < 9; ++kf) {
        float dy = omb[2 * kf], dx = omb[2 * kf + 1];
        float mr = omb[18 + kf];
        float m = 1.0f / (1.0f + __expf(-mr));
        float py  = (float)(h - 1 + kf / 3) + dy;
        float pxf = (float)(wg - 1 + kf % 3) + dx;
        float y0f = floorf(py), x0f = floorf(pxf);
        float wy1 = py - y0f, wx1 = pxf - x0f;
        float wy0 = 1.f - wy1, wx0 = 1.f - wx1;
        int y0 = (int)y0f, x0 = (int)x0f;
        float my0 = ((unsigned)y0 < 128u) ? m : 0.f;
        float my1 = ((unsigned)(y0 + 1) < 128u) ? m : 0.f;
        float vx0 = ((unsigned)x0 < 128u) ? 1.f : 0.f;
        float vx1 = ((unsigned)(x0 + 1) < 128u) ? 1.f : 0.f;
        float w00 = wy0 * wx0 * my0 * vx0, w01 = wy0 * wx1 * my0 * vx1;
        float w10 = wy1 * wx0 * my1 * vx0, w11 = wy1 * wx1 * my1 * vx1;
        int y0c = min(max(y0, 0), 127) * 8192;
        int y1c = min(max(y0 + 1, 0), 127) * 8192;
        int x0c = min(max(x0, 0), 127) * 64;
        int x1c = min(max(x0 + 1, 0), 127) * 64;
        int o00 = y0c + x0c, o01 = y0c + x1c;
        int o10 = y1c + x0c, o11 = y1c + x1c;
#pragma unroll
        for (int s = 0; s < 2; ++s) {
            int cb = s * 32 + g4 * 8;
            short8 v00 = *(const short8*)(xTb + o00 + cb);
            short8 v01 = *(const short8*)(xTb + o01 + cb);
            short8 v10 = *(const short8*)(xTb + o10 + cb);
            short8 v11 = *(const short8*)(xTb + o11 + cb);
            short8 bfrag;
            unsigned int* bu = (unsigned int*)&bfrag;
#pragma unroll
            for (int j = 0; j < 4; ++j) {
                float f0 = w00 * bf2f_s(v00[2 * j])     + w01 * bf2f_s(v01[2 * j])
                         + w10 * bf2f_s(v10[2 * j])     + w11 * bf2f_s(v11[2 * j]);
                float f1 = w00 * bf2f_s(v00[2 * j + 1]) + w01 * bf2f_s(v01[2 * j + 1])
                         + w10 * bf2f_s(v10[2 * j + 1]) + w11 * bf2f_s(v11[2 * j + 1]);
                bu[j] = cvt_pk_bf16(f0, f1);
            }
            const unsigned short* wp = wbase + kf * 64 + s * 32;
            short8 a0 = *(const short8*)(wp);
            short8 a1 = *(const short8*)(wp + 9216);
            short8 a2 = *(const short8*)(wp + 18432);
            short8 a3 = *(const short8*)(wp + 27648);
            acc0 = __builtin_amdgcn_mfma_f32_16x16x32_bf16(a0, bfrag, acc0, 0, 0, 0);
            acc1 = __builtin_amdgcn_mfma_f32_16x16x32_bf16(a1, bfrag, acc1, 0, 0, 0);
            acc2 = __builtin_amdgcn_mfma_f32_16x16x32_bf16(a2, bfrag, acc2, 0, 0, 0);
            acc3 = __builtin_amdgcn_mfma_f32_16x16x32_bf16(a3, bfrag, acc3, 0, 0, 0);
        }
    }

    // ---- store: lane (l15,g4), tile m: out rows m*16+g4*4+r, col = w0+pxl ----
    float* obp = out + (size_t)b * COUT * HW + (size_t)h * WW + wg;
    int or0 = g4 * 4;
#pragma unroll
    for (int r = 0; r < 4; ++r) {
        obp[(size_t)(or0 + r) * HW]      = acc0[r];
        obp[(size_t)(16 + or0 + r) * HW] = acc1[r];
        obp[(size_t)(32 + or0 + r) * HW] = acc2[r];
        obp[(size_t)(48 + or0 + r) * HW] = acc3[r];
    }
}

extern "C" void kernel_launch(void* const* d_in, const int* in_sizes, int n_in,
                              void* d_out, int out_size, void* d_ws, size_t ws_size,
                              hipStream_t stream) {
    (void)in_sizes; (void)n_in; (void)out_size; (void)ws_size;
    const float* x        = (const float*)d_in[0];
    const float* w_offset = (const float*)d_in[1];
    const float* b_offset = (const float*)d_in[2];
    const float* w_dcn    = (const float*)d_in[3];
    float* out = (float*)d_out;

    unsigned short* xT    = (unsigned short*)d_ws;                      // 16,777,216 B
    unsigned short* wt    = (unsigned short*)((char*)d_ws + 16777216);  // 73,728 B
    unsigned short* wtoff = (unsigned short*)((char*)d_ws + 16850944);  // 36,864 B

    xpose_kernel<<<4096, 256, 0, stream>>>(x, xT);
    wcast_kernel<<<216, 256, 0, stream>>>(w_dcn, w_offset, wt, wtoff);
    fused_dcn_kernel<<<2048, 256, 0, stream>>>(xT, wtoff, b_offset, wt, out);
}

// Round 8
// 137.134 us; speedup vs baseline: 1.3904x; 1.3904x over previous
//
#include <hip/hip_runtime.h>
#include <math.h>

#define BATCH 8
#define CIN 64
#define COUT 64
#define HH 128
#define WW 128
#define HW (HH*WW)
#define TPX 64       // pixels per block (half row)
#define KDIM 576     // K index = kf*64 + c
#define NR 5         // staged rows  (h-2 .. h+2, clamped)
#define NC 69        // staged cols  (w0-2 .. w0+66, clamped)
#define NSLOT (NR*NC)          // 345 col-slots
#define NITEM (NSLOT*8)        // 2760 16B-chunks

typedef __attribute__((ext_vector_type(8))) short short8;
typedef __attribute__((ext_vector_type(4))) float f32x4;

__device__ __forceinline__ unsigned short f2bf(float f) {
    union { float f; unsigned int u; } v; v.f = f;
    unsigned int u = v.u;
    u += 0x7FFFu + ((u >> 16) & 1u);   // RNE
    return (unsigned short)(u >> 16);
}
__device__ __forceinline__ float bf2f_s(short s) {
    union { unsigned int u; float f; } v;
    v.u = ((unsigned int)(unsigned short)s) << 16;
    return v.f;
}
__device__ __forceinline__ unsigned int cvt_pk_bf16(float lo, float hi) {
    unsigned int r;
    asm("v_cvt_pk_bf16_f32 %0, %1, %2" : "=v"(r) : "v"(lo), "v"(hi));
    return r;
}

// ---------------- Kernel 1: x[b][c][h][w] fp32 -> xT[b][h][w][c] bf16 ----------------
__global__ void __launch_bounds__(256) xpose_kernel(const float* __restrict__ x,
                                                    unsigned short* __restrict__ xT) {
    int idx = blockIdx.x * 256 + threadIdx.x;   // 1,048,576 total
    int c8 = idx & 7;
    int w  = (idx >> 3) & 127;
    int h  = (idx >> 10) & 127;
    int b  = idx >> 17;
    const float* xp = x + (((size_t)(b * 64 + c8 * 8) * 128 + h) * 128 + w);
    short8 o;
    unsigned int* ou = (unsigned int*)&o;
#pragma unroll
    for (int j = 0; j < 4; ++j)
        ou[j] = cvt_pk_bf16(xp[(size_t)(2 * j) * HW], xp[(size_t)(2 * j + 1) * HW]);
    *(short8*)(xT + (size_t)idx * 8) = o;
}

// ---------------- Kernel 2: weight casts/reorders to [o][kf*64+c] bf16 ----------------
__global__ void __launch_bounds__(256) wcast_kernel(const float* __restrict__ w_dcn,
                                                    const float* __restrict__ w_off,
                                                    unsigned short* __restrict__ wt,
                                                    unsigned short* __restrict__ wtoff) {
    int i = blockIdx.x * 256 + threadIdx.x;
    if (i < COUT * KDIM) {
        int o = i / KDIM, k = i % KDIM;
        int kf = k >> 6, c = k & 63;
        wt[i] = f2bf(w_dcn[(o * 64 + c) * 9 + kf]);
    } else {
        int i2 = i - COUT * KDIM;
        if (i2 < 32 * KDIM) {
            int o = i2 / KDIM, k = i2 % KDIM;
            int kf = k >> 6, c = k & 63;
            wtoff[i2] = (o < 27) ? f2bf(w_off[(o * 64 + c) * 9 + kf]) : (unsigned short)0;
        }
    }
}

// ---------------- Kernel 3: fused, LDS x-tile + register gather -> MFMA ----------------
// Block = 64 px (half row), 4 waves; wave wv owns px 16wv..16wv+15, all 64 outs.
// x window rows h-2..h+2, cols w0-2..w0+66 staged in LDS (clamped addresses;
// out-of-image handled by zero weights / zero-masked conv frags). Samples whose
// corners fall outside the window (|offset|>~1) take a rare global fallback.
__global__ void __launch_bounds__(256, 3) fused_dcn_kernel(
        const unsigned short* __restrict__ xT,
        const unsigned short* __restrict__ wtoff,
        const float* __restrict__ b_off,
        const unsigned short* __restrict__ wt,
        float* __restrict__ out) {
    __shared__ char  s_x[NSLOT * 128];          // 44,160 B  [r5][c][chunk^ (c&7)]
    __shared__ float s_om[TPX * 29];            // 7,424 B

    int t = threadIdx.x;
    int blk0 = blockIdx.x;
    int blk = (blk0 & 7) * 256 + (blk0 >> 3);   // XCD swizzle (2048 = 8*256, bijective)
    int b = blk >> 8;
    int rem = blk & 255;
    int h = rem >> 1;
    int w0 = (rem & 1) << 6;

    int lane = t & 63;
    int wv = t >> 6;
    int l15 = lane & 15;
    int g4 = lane >> 4;
    int pxl = wv * 16 + l15;                    // local pixel 0..63
    int wg = w0 + pxl;                          // global col

    const unsigned short* xTb = xT + (size_t)b * HW * 64;

    // ---- phase 0: stage x window into LDS (issue-early / write-late) ----
    {
        short8 v[11];
        int cs[11], cl[11];
#pragma unroll
        for (int it = 0; it < 11; ++it) {
            int i = it * 256 + t;
            if (i < NITEM) {
                int c_slot = i >> 3;
                cl[it] = i & 7;
                int r5 = c_slot / NC;
                int c  = c_slot - r5 * NC;
                cs[it] = c_slot;
                int row_src = min(max(h - 2 + r5, 0), 127);
                int col_src = min(max(w0 - 2 + c, 0), 127);
                v[it] = *(const short8*)(xTb + ((size_t)row_src * 128 + col_src) * 64 + cl[it] * 8);
            }
        }
#pragma unroll
        for (int it = 0; it < 11; ++it) {
            int i = it * 256 + t;
            if (i < NITEM) {
                int c_slot = cs[it];
                int c = c_slot - (c_slot / NC) * NC;
                int baddr = c_slot * 128 + ((cl[it] ^ (c & 7)) << 4);
                *(short8*)(s_x + baddr) = v[it];
            }
        }
    }
    __syncthreads();

    // ---- phase A: offset conv (27ch) via MFMA, x from LDS ----
    {
        f32x4 ca0 = {0.f, 0.f, 0.f, 0.f};
        f32x4 ca1 = {0.f, 0.f, 0.f, 0.f};
        const unsigned short* ar0 = wtoff + (size_t)l15 * KDIM;
        const unsigned short* ar1 = wtoff + (size_t)(16 + l15) * KDIM;
#pragma unroll
        for (int kk = 0; kk < 18; ++kk) {
            int kf = kk >> 1;
            int ky = kf / 3, kx = kf % 3;
            int cq = (kk & 1) * 4 + g4;
            int row = h - 1 + ky;
            int col = wg - 1 + kx;
            int cc = pxl + 1 + kx;              // window col index
            int addr = ((ky + 1) * NC + cc) * 128 + ((cq ^ (cc & 7)) << 4);
            short8 bfrag = *(const short8*)(s_x + addr);
            if (!((unsigned)row < 128u && (unsigned)col < 128u))
                bfrag = (short8){0, 0, 0, 0, 0, 0, 0, 0};
            short8 a0 = *(const short8*)(ar0 + kk * 32 + g4 * 8);
            short8 a1 = *(const short8*)(ar1 + kk * 32 + g4 * 8);
            ca0 = __builtin_amdgcn_mfma_f32_16x16x32_bf16(a0, bfrag, ca0, 0, 0, 0);
            ca1 = __builtin_amdgcn_mfma_f32_16x16x32_bf16(a1, bfrag, ca1, 0, 0, 0);
        }
        int ch0 = g4 * 4;
#pragma unroll
        for (int r = 0; r < 4; ++r) {
            s_om[pxl * 29 + ch0 + r] = ca0[r] + b_off[ch0 + r];
            if (ch0 + 16 + r < 27)
                s_om[pxl * 29 + 16 + ch0 + r] = ca1[r] + b_off[16 + ch0 + r];
        }
    }
    __syncthreads();

    // ---- main loop ----
    f32x4 acc0 = {0.f, 0.f, 0.f, 0.f};
    f32x4 acc1 = {0.f, 0.f, 0.f, 0.f};
    f32x4 acc2 = {0.f, 0.f, 0.f, 0.f};
    f32x4 acc3 = {0.f, 0.f, 0.f, 0.f};
    const unsigned short* wbase = wt + (size_t)l15 * KDIM + g4 * 8;
    const float* omb = s_om + pxl * 29;

#pragma unroll
    for (int kf = 0; kf < 9; ++kf) {
        // prefetch all 8 A-fragments for this kf (independent global loads)
        short8 a[2][4];
#pragma unroll
        for (int s = 0; s < 2; ++s)
#pragma unroll
            for (int m = 0; m < 4; ++m)
                a[s][m] = *(const short8*)(wbase + kf * 64 + s * 32 + m * 16 * KDIM);

        float dy = omb[2 * kf], dx = omb[2 * kf + 1];
        float mr = omb[18 + kf];
        float m = 1.0f / (1.0f + __expf(-mr));
        float py  = (float)(h - 1 + kf / 3) + dy;
        float pxf = (float)(wg - 1 + kf % 3) + dx;
        float y0f = floorf(py), x0f = floorf(pxf);
        float wy1 = py - y0f, wx1 = pxf - x0f;
        float wy0 = 1.f - wy1, wx0 = 1.f - wx1;
        int y0 = (int)y0f, x0 = (int)x0f;
        float my0 = ((unsigned)y0 < 128u) ? m : 0.f;
        float my1 = ((unsigned)(y0 + 1) < 128u) ? m : 0.f;
        float vx0 = ((unsigned)x0 < 128u) ? 1.f : 0.f;
        float vx1 = ((unsigned)(x0 + 1) < 128u) ? 1.f : 0.f;
        float w00 = wy0 * wx0 * my0 * vx0, w01 = wy0 * wx1 * my0 * vx1;
        float w10 = wy1 * wx0 * my1 * vx0, w11 = wy1 * wx1 * my1 * vx1;

        int r50 = y0 - (h - 2);                 // window row of top corners
        int c0  = x0 - (w0 - 2);                // window col of left corners
        bool inw = (r50 >= 0) && (r50 <= 3) && (c0 >= 0) && (c0 <= 67);
        int a00 = (r50 * NC + c0) * 128;
        int a01 = a00 + 128;
        int a10 = a00 + NC * 128;
        int a11 = a10 + 128;
        int sw0 = (c0 & 7) << 4;
        int sw1 = ((c0 + 1) & 7) << 4;

#pragma unroll
        for (int s = 0; s < 2; ++s) {
            int q4 = (s * 4 + g4) << 4;
            short8 v00, v01, v10, v11;
            if (inw) {
                v00 = *(const short8*)(s_x + a00 + (q4 ^ sw0));
                v01 = *(const short8*)(s_x + a01 + (q4 ^ sw1));
                v10 = *(const short8*)(s_x + a10 + (q4 ^ sw0));
                v11 = *(const short8*)(s_x + a11 + (q4 ^ sw1));
            } else {                            // rare: sample outside staged window
                int cb = s * 32 + g4 * 8;
                int y0c = min(max(y0, 0), 127) * 8192;
                int y1c = min(max(y0 + 1, 0), 127) * 8192;
                int x0c = min(max(x0, 0), 127) * 64;
                int x1c = min(max(x0 + 1, 0), 127) * 64;
                v00 = *(const short8*)(xTb + y0c + x0c + cb);
                v01 = *(const short8*)(xTb + y0c + x1c + cb);
                v10 = *(const short8*)(xTb + y1c + x0c + cb);
                v11 = *(const short8*)(xTb + y1c + x1c + cb);
            }
            short8 bfrag;
            unsigned int* bu = (unsigned int*)&bfrag;
#pragma unroll
            for (int j = 0; j < 4; ++j) {
                float f0 = w00 * bf2f_s(v00[2 * j])     + w01 * bf2f_s(v01[2 * j])
                         + w10 * bf2f_s(v10[2 * j])     + w11 * bf2f_s(v11[2 * j]);
                float f1 = w00 * bf2f_s(v00[2 * j + 1]) + w01 * bf2f_s(v01[2 * j + 1])
                         + w10 * bf2f_s(v10[2 * j + 1]) + w11 * bf2f_s(v11[2 * j + 1]);
                bu[j] = cvt_pk_bf16(f0, f1);
            }
            acc0 = __builtin_amdgcn_mfma_f32_16x16x32_bf16(a[s][0], bfrag, acc0, 0, 0, 0);
            acc1 = __builtin_amdgcn_mfma_f32_16x16x32_bf16(a[s][1], bfrag, acc1, 0, 0, 0);
            acc2 = __builtin_amdgcn_mfma_f32_16x16x32_bf16(a[s][2], bfrag, acc2, 0, 0, 0);
            acc3 = __builtin_amdgcn_mfma_f32_16x16x32_bf16(a[s][3], bfrag, acc3, 0, 0, 0);
        }
    }

    // ---- store ----
    float* obp = out + (size_t)b * COUT * HW + (size_t)h * WW + wg;
    int or0 = g4 * 4;
#pragma unroll
    for (int r = 0; r < 4; ++r) {
        obp[(size_t)(or0 + r) * HW]      = acc0[r];
        obp[(size_t)(16 + or0 + r) * HW] = acc1[r];
        obp[(size_t)(32 + or0 + r) * HW] = acc2[r];
        obp[(size_t)(48 + or0 + r) * HW] = acc3[r];
    }
}

extern "C" void kernel_launch(void* const* d_in, const int* in_sizes, int n_in,
                              void* d_out, int out_size, void* d_ws, size_t ws_size,
                              hipStream_t stream) {
    (void)in_sizes; (void)n_in; (void)out_size; (void)ws_size;
    const float* x        = (const float*)d_in[0];
    const float* w_offset = (const float*)d_in[1];
    const float* b_offset = (const float*)d_in[2];
    const float* w_dcn    = (const float*)d_in[3];
    float* out = (float*)d_out;

    unsigned short* xT    = (unsigned short*)d_ws;                      // 16,777,216 B
    unsigned short* wt    = (unsigned short*)((char*)d_ws + 16777216);  // 73,728 B
    unsigned short* wtoff = (unsigned short*)((char*)d_ws + 16850944);  // 36,864 B

    xpose_kernel<<<4096, 256, 0, stream>>>(x, xT);
    wcast_kernel<<<216, 256, 0, stream>>>(w_dcn, w_offset, wt, wtoff);
    fused_dcn_kernel<<<2048, 256, 0, stream>>>(xT, wtoff, b_offset, wt, out);
}

// Round 9
// 74.845 us; speedup vs baseline: 2.5475x; 1.8322x over previous
//
#include <hip/hip_runtime.h>
#include <math.h>

#define BATCH 8
#define CIN 64
#define COUT 64
#define HH 128
#define WW 128
#define HW (HH*WW)
#define TPX 64       // pixels per block (half row)
#define KDIM 576
#define NR 5         // staged rows  (h-2 .. h+2, clamped)
#define NC 69        // staged cols  (w0-2 .. w0+66, clamped)
#define NSLOT (NR*NC)          // 345 col-slots
#define NITEM (NSLOT*8)        // 2760 16B-chunks

typedef __attribute__((ext_vector_type(8))) short short8;
typedef __attribute__((ext_vector_type(4))) float f32x4;

__device__ __forceinline__ unsigned short f2bf(float f) {
    union { float f; unsigned int u; } v; v.f = f;
    unsigned int u = v.u;
    u += 0x7FFFu + ((u >> 16) & 1u);   // RNE
    return (unsigned short)(u >> 16);
}
__device__ __forceinline__ float bf2f_s(short s) {
    union { unsigned int u; float f; } v;
    v.u = ((unsigned int)(unsigned short)s) << 16;
    return v.f;
}
__device__ __forceinline__ unsigned int cvt_pk_bf16(float lo, float hi) {
    unsigned int r;
    asm("v_cvt_pk_bf16_f32 %0, %1, %2" : "=v"(r) : "v"(lo), "v"(hi));
    return r;
}

// ---------------- Kernel 1: x[b][c][h][w] fp32 -> xT[b][h][w][c] bf16 ----------------
__global__ void __launch_bounds__(256) xpose_kernel(const float* __restrict__ x,
                                                    unsigned short* __restrict__ xT) {
    int idx = blockIdx.x * 256 + threadIdx.x;   // 1,048,576 total
    int c8 = idx & 7;
    int w  = (idx >> 3) & 127;
    int h  = (idx >> 10) & 127;
    int b  = idx >> 17;
    const float* xp = x + (((size_t)(b * 64 + c8 * 8) * 128 + h) * 128 + w);
    short8 o;
    unsigned int* ou = (unsigned int*)&o;
#pragma unroll
    for (int j = 0; j < 4; ++j)
        ou[j] = cvt_pk_bf16(xp[(size_t)(2 * j) * HW], xp[(size_t)(2 * j + 1) * HW]);
    *(short8*)(xT + (size_t)idx * 8) = o;
}

// ---------------- Kernel 2: weights -> MFMA-fragment order ----------------
// wt2   : 72 frags [(kf*2+s)*4+m][lane][8]   (main conv weights)
// wtoff2: 36 frags [kk*2+m][lane][8]         (offset conv weights, rows>=27 zero)
// A-fragment lane mapping (16x16x32): row = lane&15, k-slice = (lane>>4)*8.
__global__ void __launch_bounds__(256) wcast_kernel(const float* __restrict__ w_dcn,
                                                    const float* __restrict__ w_off,
                                                    unsigned short* __restrict__ wt2,
                                                    unsigned short* __restrict__ wtoff2) {
    int gid = blockIdx.x * 256 + threadIdx.x;
    if (gid < 72 * 64) {
        int frag = gid >> 6, lane = gid & 63;
        int kf = frag >> 3, s = (frag >> 2) & 1, m = frag & 3;
        int o = m * 16 + (lane & 15);
        int cb = s * 32 + (lane >> 4) * 8;
        short8 v;
#pragma unroll
        for (int j = 0; j < 8; ++j)
            v[j] = (short)f2bf(w_dcn[(o * 64 + cb + j) * 9 + kf]);
        *(short8*)(wt2 + (size_t)gid * 8) = v;
    } else {
        int g2 = gid - 72 * 64;
        if (g2 < 36 * 64) {
            int frag = g2 >> 6, lane = g2 & 63;
            int kk = frag >> 1, m = frag & 1;
            int kf = kk >> 1;
            int o = m * 16 + (lane & 15);
            int cb = (kk & 1) * 32 + (lane >> 4) * 8;
            short8 v;
#pragma unroll
            for (int j = 0; j < 8; ++j)
                v[j] = (o < 27) ? (short)f2bf(w_off[(o * 64 + cb + j) * 9 + kf]) : (short)0;
            *(short8*)(wtoff2 + (size_t)g2 * 8) = v;
        }
    }
}

// ---------------- Kernel 3: fused, LDS x-tile + coalesced A-frags -> MFMA ----------------
__global__ void __launch_bounds__(256, 3) fused_dcn_kernel(
        const unsigned short* __restrict__ xT,
        const unsigned short* __restrict__ wtoff2,
        const float* __restrict__ b_off,
        const unsigned short* __restrict__ wt2,
        float* __restrict__ out) {
    __shared__ char  s_x[NSLOT * 128];          // 44,160 B  [slot][chunk ^ (c&7)]
    __shared__ float s_om[TPX * 29];            // 7,424 B

    int t = threadIdx.x;
    int blk0 = blockIdx.x;
    int blk = (blk0 & 7) * 256 + (blk0 >> 3);   // XCD swizzle (2048 = 8*256, bijective)
    int b = blk >> 8;
    int rem = blk & 255;
    int h = rem >> 1;
    int w0 = (rem & 1) << 6;

    int lane = t & 63;
    int wv = t >> 6;
    int l15 = lane & 15;
    int g4 = lane >> 4;
    int pxl = wv * 16 + l15;                    // local pixel 0..63
    int wg = w0 + pxl;                          // global col

    const unsigned short* xTb = xT + (size_t)b * HW * 64;

    // ---- phase 0: stage x window into LDS (issue-early / write-late) ----
    {
        short8 v[11];
        int cs[11], cl[11];
#pragma unroll
        for (int it = 0; it < 11; ++it) {
            int i = it * 256 + t;
            if (i < NITEM) {
                int c_slot = i >> 3;
                cl[it] = i & 7;
                int r5 = c_slot / NC;
                int c  = c_slot - r5 * NC;
                cs[it] = c_slot;
                int row_src = min(max(h - 2 + r5, 0), 127);
                int col_src = min(max(w0 - 2 + c, 0), 127);
                v[it] = *(const short8*)(xTb + ((size_t)row_src * 128 + col_src) * 64 + cl[it] * 8);
            }
        }
#pragma unroll
        for (int it = 0; it < 11; ++it) {
            int i = it * 256 + t;
            if (i < NITEM) {
                int c_slot = cs[it];
                int c = c_slot - (c_slot / NC) * NC;
                int baddr = c_slot * 128 + ((cl[it] ^ (c & 7)) << 4);
                *(short8*)(s_x + baddr) = v[it];
            }
        }
    }
    __syncthreads();

    // ---- phase A: offset conv (27ch) via MFMA, x from LDS, coalesced A ----
    {
        f32x4 ca0 = {0.f, 0.f, 0.f, 0.f};
        f32x4 ca1 = {0.f, 0.f, 0.f, 0.f};
#pragma unroll
        for (int kk = 0; kk < 18; ++kk) {
            int kf = kk >> 1;
            int ky = kf / 3, kx = kf % 3;
            int cq = (kk & 1) * 4 + g4;
            int row = h - 1 + ky;
            int col = wg - 1 + kx;
            int cc = pxl + 1 + kx;              // window col index
            int addr = ((ky + 1) * NC + cc) * 128 + ((cq ^ (cc & 7)) << 4);
            short8 bfrag = *(const short8*)(s_x + addr);
            if (!((unsigned)row < 128u && (unsigned)col < 128u))
                bfrag = (short8){0, 0, 0, 0, 0, 0, 0, 0};
            short8 a0 = *(const short8*)(wtoff2 + (size_t)(kk * 2 + 0) * 512 + lane * 8);
            short8 a1 = *(const short8*)(wtoff2 + (size_t)(kk * 2 + 1) * 512 + lane * 8);
            ca0 = __builtin_amdgcn_mfma_f32_16x16x32_bf16(a0, bfrag, ca0, 0, 0, 0);
            ca1 = __builtin_amdgcn_mfma_f32_16x16x32_bf16(a1, bfrag, ca1, 0, 0, 0);
        }
        int ch0 = g4 * 4;
#pragma unroll
        for (int r = 0; r < 4; ++r) {
            s_om[pxl * 29 + ch0 + r] = ca0[r] + b_off[ch0 + r];
            if (ch0 + 16 + r < 27)
                s_om[pxl * 29 + 16 + ch0 + r] = ca1[r] + b_off[16 + ch0 + r];
        }
    }
    __syncthreads();

    // ---- main loop: software-pipelined coalesced A-frags ----
    f32x4 acc0 = {0.f, 0.f, 0.f, 0.f};
    f32x4 acc1 = {0.f, 0.f, 0.f, 0.f};
    f32x4 acc2 = {0.f, 0.f, 0.f, 0.f};
    f32x4 acc3 = {0.f, 0.f, 0.f, 0.f};
    const float* omb = s_om + pxl * 29;

    short8 a_cur[8], a_nxt[8];
#pragma unroll
    for (int q = 0; q < 8; ++q)
        a_cur[q] = *(const short8*)(wt2 + (size_t)q * 512 + lane * 8);

#pragma unroll
    for (int kf = 0; kf < 9; ++kf) {
        if (kf < 8) {
#pragma unroll
            for (int q = 0; q < 8; ++q)
                a_nxt[q] = *(const short8*)(wt2 + (size_t)((kf + 1) * 8 + q) * 512 + lane * 8);
        }

        float dy = omb[2 * kf], dx = omb[2 * kf + 1];
        float mr = omb[18 + kf];
        float m = 1.0f / (1.0f + __expf(-mr));
        float py  = (float)(h - 1 + kf / 3) + dy;
        float pxf = (float)(wg - 1 + kf % 3) + dx;
        float y0f = floorf(py), x0f = floorf(pxf);
        float wy1 = py - y0f, wx1 = pxf - x0f;
        float wy0 = 1.f - wy1, wx0 = 1.f - wx1;
        int y0 = (int)y0f, x0 = (int)x0f;
        float my0 = ((unsigned)y0 < 128u) ? m : 0.f;
        float my1 = ((unsigned)(y0 + 1) < 128u) ? m : 0.f;
        float vx0 = ((unsigned)x0 < 128u) ? 1.f : 0.f;
        float vx1 = ((unsigned)(x0 + 1) < 128u) ? 1.f : 0.f;
        float w00 = wy0 * wx0 * my0 * vx0, w01 = wy0 * wx1 * my0 * vx1;
        float w10 = wy1 * wx0 * my1 * vx0, w11 = wy1 * wx1 * my1 * vx1;

        int r50 = y0 - (h - 2);                 // window row of top corners
        int c0  = x0 - (w0 - 2);                // window col of left corners
        bool inw = (r50 >= 0) && (r50 <= 3) && (c0 >= 0) && (c0 <= 67);
        int a00 = (r50 * NC + c0) * 128;
        int a01 = a00 + 128;
        int a10 = a00 + NC * 128;
        int a11 = a10 + 128;
        int sw0 = (c0 & 7) << 4;
        int sw1 = ((c0 + 1) & 7) << 4;

#pragma unroll
        for (int s = 0; s < 2; ++s) {
            int q4 = (s * 4 + g4) << 4;
            short8 v00, v01, v10, v11;
            if (inw) {
                v00 = *(const short8*)(s_x + a00 + (q4 ^ sw0));
                v01 = *(const short8*)(s_x + a01 + (q4 ^ sw1));
                v10 = *(const short8*)(s_x + a10 + (q4 ^ sw0));
                v11 = *(const short8*)(s_x + a11 + (q4 ^ sw1));
            } else {                            // rare: sample outside staged window
                int cb = s * 32 + g4 * 8;
                int y0c = min(max(y0, 0), 127) * 8192;
                int y1c = min(max(y0 + 1, 0), 127) * 8192;
                int x0c = min(max(x0, 0), 127) * 64;
                int x1c = min(max(x0 + 1, 0), 127) * 64;
                v00 = *(const short8*)(xTb + y0c + x0c + cb);
                v01 = *(const short8*)(xTb + y0c + x1c + cb);
                v10 = *(const short8*)(xTb + y1c + x0c + cb);
                v11 = *(const short8*)(xTb + y1c + x1c + cb);
            }
            short8 bfrag;
            unsigned int* bu = (unsigned int*)&bfrag;
#pragma unroll
            for (int j = 0; j < 4; ++j) {
                float f0 = w00 * bf2f_s(v00[2 * j])     + w01 * bf2f_s(v01[2 * j])
                         + w10 * bf2f_s(v10[2 * j])     + w11 * bf2f_s(v11[2 * j]);
                float f1 = w00 * bf2f_s(v00[2 * j + 1]) + w01 * bf2f_s(v01[2 * j + 1])
                         + w10 * bf2f_s(v10[2 * j + 1]) + w11 * bf2f_s(v11[2 * j + 1]);
                bu[j] = cvt_pk_bf16(f0, f1);
            }
            acc0 = __builtin_amdgcn_mfma_f32_16x16x32_bf16(a_cur[s * 4 + 0], bfrag, acc0, 0, 0, 0);
            acc1 = __builtin_amdgcn_mfma_f32_16x16x32_bf16(a_cur[s * 4 + 1], bfrag, acc1, 0, 0, 0);
            acc2 = __builtin_amdgcn_mfma_f32_16x16x32_bf16(a_cur[s * 4 + 2], bfrag, acc2, 0, 0, 0);
            acc3 = __builtin_amdgcn_mfma_f32_16x16x32_bf16(a_cur[s * 4 + 3], bfrag, acc3, 0, 0, 0);
        }
#pragma unroll
        for (int q = 0; q < 8; ++q)
            a_cur[q] = a_nxt[q];
    }

    // ---- store ----
    float* obp = out + (size_t)b * COUT * HW + (size_t)h * WW + wg;
    int or0 = g4 * 4;
#pragma unroll
    for (int r = 0; r < 4; ++r) {
        obp[(size_t)(or0 + r) * HW]      = acc0[r];
        obp[(size_t)(16 + or0 + r) * HW] = acc1[r];
        obp[(size_t)(32 + or0 + r) * HW] = acc2[r];
        obp[(size_t)(48 + or0 + r) * HW] = acc3[r];
    }
}

extern "C" void kernel_launch(void* const* d_in, const int* in_sizes, int n_in,
                              void* d_out, int out_size, void* d_ws, size_t ws_size,
                              hipStream_t stream) {
    (void)in_sizes; (void)n_in; (void)out_size; (void)ws_size;
    const float* x        = (const float*)d_in[0];
    const float* w_offset = (const float*)d_in[1];
    const float* b_offset = (const float*)d_in[2];
    const float* w_dcn    = (const float*)d_in[3];
    float* out = (float*)d_out;

    unsigned short* xT     = (unsigned short*)d_ws;                      // 16,777,216 B
    unsigned short* wt2    = (unsigned short*)((char*)d_ws + 16777216);  // 73,728 B
    unsigned short* wtoff2 = (unsigned short*)((char*)d_ws + 16850944);  // 36,864 B

    xpose_kernel<<<4096, 256, 0, stream>>>(x, xT);
    wcast_kernel<<<27, 256, 0, stream>>>(w_dcn, w_offset, wt2, wtoff2);
    fused_dcn_kernel<<<2048, 256, 0, stream>>>(xT, wtoff2, b_offset, wt2, out);
}

// Round 10
// 63.803 us; speedup vs baseline: 2.9884x; 1.1731x over previous
//
#include <hip/hip_runtime.h>
#include <math.h>

#define BATCH 8
#define CIN 64
#define COUT 64
#define HH 128
#define WW 128
#define HW (HH*WW)
#define TPX 64       // pixels per block (half row)
#define KDIM 576
#define NR 5         // staged rows  (h-2 .. h+2, clamped)
#define NC 69        // staged cols  (w0-2 .. w0+66, clamped)
#define NSLOT (NR*NC)          // 345 col-slots
#define NITEM (NSLOT*8)        // 2760 16B-chunks

typedef __attribute__((ext_vector_type(8))) short short8;
typedef __attribute__((ext_vector_type(4))) float f32x4;
typedef _Float16 h2   __attribute__((ext_vector_type(2)));
typedef _Float16 h8   __attribute__((ext_vector_type(8)));

__device__ __forceinline__ short f2h(float f) {
    union { _Float16 h; short s; } u;
    u.h = (_Float16)f;
    return u.s;
}

// ---------------- Kernel 1: x[b][c][h][w] fp32 -> xT[b][h][w][c] fp16 ----------------
__global__ void __launch_bounds__(256) xpose_kernel(const float* __restrict__ x,
                                                    unsigned short* __restrict__ xT) {
    int idx = blockIdx.x * 256 + threadIdx.x;   // 1,048,576 total
    int c8 = idx & 7;
    int w  = (idx >> 3) & 127;
    int h  = (idx >> 10) & 127;
    int b  = idx >> 17;
    const float* xp = x + (((size_t)(b * 64 + c8 * 8) * 128 + h) * 128 + w);
    short8 o;
#pragma unroll
    for (int j = 0; j < 8; ++j)
        o[j] = f2h(xp[(size_t)j * HW]);
    *(short8*)(xT + (size_t)idx * 8) = o;
}

// ---------------- Kernel 2: weights -> MFMA-fragment order, fp16 ----------------
// wt2   : 72 frags [(kf*2+s)*4+m][lane][8]   (main conv weights)
// wtoff2: 36 frags [kk*2+m][lane][8]         (offset conv weights, rows>=27 zero)
__global__ void __launch_bounds__(256) wcast_kernel(const float* __restrict__ w_dcn,
                                                    const float* __restrict__ w_off,
                                                    unsigned short* __restrict__ wt2,
                                                    unsigned short* __restrict__ wtoff2) {
    int gid = blockIdx.x * 256 + threadIdx.x;
    if (gid < 72 * 64) {
        int frag = gid >> 6, lane = gid & 63;
        int kf = frag >> 3, s = (frag >> 2) & 1, m = frag & 3;
        int o = m * 16 + (lane & 15);
        int cb = s * 32 + (lane >> 4) * 8;
        short8 v;
#pragma unroll
        for (int j = 0; j < 8; ++j)
            v[j] = f2h(w_dcn[(o * 64 + cb + j) * 9 + kf]);
        *(short8*)(wt2 + (size_t)gid * 8) = v;
    } else {
        int g2 = gid - 72 * 64;
        if (g2 < 36 * 64) {
            int frag = g2 >> 6, lane = g2 & 63;
            int kk = frag >> 1, m = frag & 1;
            int kf = kk >> 1;
            int o = m * 16 + (lane & 15);
            int cb = (kk & 1) * 32 + (lane >> 4) * 8;
            short8 v;
#pragma unroll
            for (int j = 0; j < 8; ++j)
                v[j] = (o < 27) ? f2h(w_off[(o * 64 + cb + j) * 9 + kf]) : (short)0;
            *(short8*)(wtoff2 + (size_t)g2 * 8) = v;
        }
    }
}

// ---------------- Kernel 3: fused, LDS x-tile + packed-f16 interp -> MFMA ----------------
__global__ void __launch_bounds__(256, 3) fused_dcn_kernel(
        const unsigned short* __restrict__ xT,
        const unsigned short* __restrict__ wtoff2,
        const float* __restrict__ b_off,
        const unsigned short* __restrict__ wt2,
        float* __restrict__ out) {
    __shared__ char  s_x[NSLOT * 128];          // 44,160 B  [slot][chunk ^ (c&7) ^ r5]
    __shared__ float s_om[TPX * 29];            // 7,424 B

    int t = threadIdx.x;
    int blk0 = blockIdx.x;
    int blk = (blk0 & 7) * 256 + (blk0 >> 3);   // XCD swizzle (2048 = 8*256, bijective)
    int b = blk >> 8;
    int rem = blk & 255;
    int h = rem >> 1;
    int w0 = (rem & 1) << 6;

    int lane = t & 63;
    int wv = t >> 6;
    int l15 = lane & 15;
    int g4 = lane >> 4;
    int pxl = wv * 16 + l15;                    // local pixel 0..63
    int wg = w0 + pxl;                          // global col

    const unsigned short* xTb = xT + (size_t)b * HW * 64;

    // ---- phase 0: stage x window into LDS (issue-early / write-late) ----
    {
        short8 v[11];
        int cs[11], cl[11];
#pragma unroll
        for (int it = 0; it < 11; ++it) {
            int i = it * 256 + t;
            if (i < NITEM) {
                int c_slot = i >> 3;
                cl[it] = i & 7;
                int r5 = c_slot / NC;
                int c  = c_slot - r5 * NC;
                cs[it] = c_slot;
                int row_src = min(max(h - 2 + r5, 0), 127);
                int col_src = min(max(w0 - 2 + c, 0), 127);
                v[it] = *(const short8*)(xTb + ((size_t)row_src * 128 + col_src) * 64 + cl[it] * 8);
            }
        }
#pragma unroll
        for (int it = 0; it < 11; ++it) {
            int i = it * 256 + t;
            if (i < NITEM) {
                int c_slot = cs[it];
                int r5 = c_slot / NC;
                int c = c_slot - r5 * NC;
                int baddr = c_slot * 128 + ((cl[it] ^ (c & 7) ^ r5) << 4);
                *(short8*)(s_x + baddr) = v[it];
            }
        }
    }
    __syncthreads();

    // ---- phase A: offset conv (27ch) via f16 MFMA, x from LDS, coalesced A ----
    {
        f32x4 ca0 = {0.f, 0.f, 0.f, 0.f};
        f32x4 ca1 = {0.f, 0.f, 0.f, 0.f};
#pragma unroll
        for (int kk = 0; kk < 18; ++kk) {
            int kf = kk >> 1;
            int ky = kf / 3, kx = kf % 3;
            int cq = (kk & 1) * 4 + g4;
            int row = h - 1 + ky;
            int col = wg - 1 + kx;
            int cc = pxl + 1 + kx;              // window col index
            int addr = ((ky + 1) * NC + cc) * 128 + ((cq ^ (cc & 7) ^ (ky + 1)) << 4);
            h8 bfrag = *(const h8*)(s_x + addr);
            if (!((unsigned)row < 128u && (unsigned)col < 128u))
                bfrag = (h8){0, 0, 0, 0, 0, 0, 0, 0};
            h8 a0 = *(const h8*)(wtoff2 + (size_t)(kk * 2 + 0) * 512 + lane * 8);
            h8 a1 = *(const h8*)(wtoff2 + (size_t)(kk * 2 + 1) * 512 + lane * 8);
            ca0 = __builtin_amdgcn_mfma_f32_16x16x32_f16(a0, bfrag, ca0, 0, 0, 0);
            ca1 = __builtin_amdgcn_mfma_f32_16x16x32_f16(a1, bfrag, ca1, 0, 0, 0);
        }
        int ch0 = g4 * 4;
#pragma unroll
        for (int r = 0; r < 4; ++r) {
            s_om[pxl * 29 + ch0 + r] = ca0[r] + b_off[ch0 + r];
            if (ch0 + 16 + r < 27)
                s_om[pxl * 29 + 16 + ch0 + r] = ca1[r] + b_off[16 + ch0 + r];
        }
    }
    __syncthreads();

    // ---- main loop: packed-f16 interp, software-pipelined A-frags ----
    f32x4 acc0 = {0.f, 0.f, 0.f, 0.f};
    f32x4 acc1 = {0.f, 0.f, 0.f, 0.f};
    f32x4 acc2 = {0.f, 0.f, 0.f, 0.f};
    f32x4 acc3 = {0.f, 0.f, 0.f, 0.f};
    const float* omb = s_om + pxl * 29;

    h8 a_cur[8], a_nxt[8];
#pragma unroll
    for (int q = 0; q < 8; ++q)
        a_cur[q] = *(const h8*)(wt2 + (size_t)q * 512 + lane * 8);

#pragma unroll
    for (int kf = 0; kf < 9; ++kf) {
        if (kf < 8) {
#pragma unroll
            for (int q = 0; q < 8; ++q)
                a_nxt[q] = *(const h8*)(wt2 + (size_t)((kf + 1) * 8 + q) * 512 + lane * 8);
        }

        float dy = omb[2 * kf], dx = omb[2 * kf + 1];
        float mr = omb[18 + kf];
        float m = 1.0f / (1.0f + __expf(-mr));
        float py  = (float)(h - 1 + kf / 3) + dy;
        float pxf = (float)(wg - 1 + kf % 3) + dx;
        float y0f = floorf(py), x0f = floorf(pxf);
        float wy1 = py - y0f, wx1 = pxf - x0f;
        float wy0 = 1.f - wy1, wx0 = 1.f - wx1;
        int y0 = (int)y0f, x0 = (int)x0f;
        float my0 = ((unsigned)y0 < 128u) ? m : 0.f;
        float my1 = ((unsigned)(y0 + 1) < 128u) ? m : 0.f;
        float vx0 = ((unsigned)x0 < 128u) ? 1.f : 0.f;
        float vx1 = ((unsigned)(x0 + 1) < 128u) ? 1.f : 0.f;
        float w00 = wy0 * wx0 * my0 * vx0, w01 = wy0 * wx1 * my0 * vx1;
        float w10 = wy1 * wx0 * my1 * vx0, w11 = wy1 * wx1 * my1 * vx1;

        _Float16 h00 = (_Float16)w00, h01 = (_Float16)w01;
        _Float16 h10 = (_Float16)w10, h11 = (_Float16)w11;
        h2 W00 = {h00, h00}, W01 = {h01, h01}, W10 = {h10, h10}, W11 = {h11, h11};

        int r50 = y0 - (h - 2);                 // window row of top corners
        int c0  = x0 - (w0 - 2);                // window col of left corners
        bool inw = (r50 >= 0) && (r50 <= 3) && (c0 >= 0) && (c0 <= 67);
        int a00 = (r50 * NC + c0) * 128;
        int a01 = a00 + 128;
        int a10 = a00 + NC * 128;
        int a11 = a10 + 128;
        int sw00 = (((c0 & 7) ^ (r50 & 7)) << 4);
        int sw01 = ((((c0 + 1) & 7) ^ (r50 & 7)) << 4);
        int sw10 = (((c0 & 7) ^ ((r50 + 1) & 7)) << 4);
        int sw11 = ((((c0 + 1) & 7) ^ ((r50 + 1) & 7)) << 4);

#pragma unroll
        for (int s = 0; s < 2; ++s) {
            int q4 = (s * 4 + g4) << 4;
            h8 v00, v01, v10, v11;
            if (inw) {
                v00 = *(const h8*)(s_x + a00 + (q4 ^ sw00));
                v01 = *(const h8*)(s_x + a01 + (q4 ^ sw01));
                v10 = *(const h8*)(s_x + a10 + (q4 ^ sw10));
                v11 = *(const h8*)(s_x + a11 + (q4 ^ sw11));
            } else {                            // rare: sample outside staged window
                int cb = s * 32 + g4 * 8;
                int y0c = min(max(y0, 0), 127) * 8192;
                int y1c = min(max(y0 + 1, 0), 127) * 8192;
                int x0c = min(max(x0, 0), 127) * 64;
                int x1c = min(max(x0 + 1, 0), 127) * 64;
                v00 = *(const h8*)(xTb + y0c + x0c + cb);
                v01 = *(const h8*)(xTb + y0c + x1c + cb);
                v10 = *(const h8*)(xTb + y1c + x0c + cb);
                v11 = *(const h8*)(xTb + y1c + x1c + cb);
            }
            h8 bfrag;
            const h2* p00 = (const h2*)&v00;
            const h2* p01 = (const h2*)&v01;
            const h2* p10 = (const h2*)&v10;
            const h2* p11 = (const h2*)&v11;
            h2* bp = (h2*)&bfrag;
#pragma unroll
            for (int j = 0; j < 4; ++j) {
                h2 r = p11[j] * W11;
                r = p10[j] * W10 + r;
                r = p01[j] * W01 + r;
                r = p00[j] * W00 + r;
                bp[j] = r;
            }
            acc0 = __builtin_amdgcn_mfma_f32_16x16x32_f16(a_cur[s * 4 + 0], bfrag, acc0, 0, 0, 0);
            acc1 = __builtin_amdgcn_mfma_f32_16x16x32_f16(a_cur[s * 4 + 1], bfrag, acc1, 0, 0, 0);
            acc2 = __builtin_amdgcn_mfma_f32_16x16x32_f16(a_cur[s * 4 + 2], bfrag, acc2, 0, 0, 0);
            acc3 = __builtin_amdgcn_mfma_f32_16x16x32_f16(a_cur[s * 4 + 3], bfrag, acc3, 0, 0, 0);
        }
#pragma unroll
        for (int q = 0; q < 8; ++q)
            a_cur[q] = a_nxt[q];
    }

    // ---- store ----
    float* obp = out + (size_t)b * COUT * HW + (size_t)h * WW + wg;
    int or0 = g4 * 4;
#pragma unroll
    for (int r = 0; r < 4; ++r) {
        obp[(size_t)(or0 + r) * HW]      = acc0[r];
        obp[(size_t)(16 + or0 + r) * HW] = acc1[r];
        obp[(size_t)(32 + or0 + r) * HW] = acc2[r];
        obp[(size_t)(48 + or0 + r) * HW] = acc3[r];
    }
}

extern "C" void kernel_launch(void* const* d_in, const int* in_sizes, int n_in,
                              void* d_out, int out_size, void* d_ws, size_t ws_size,
                              hipStream_t stream) {
    (void)in_sizes; (void)n_in; (void)out_size; (void)ws_size;
    const float* x        = (const float*)d_in[0];
    const float* w_offset = (const float*)d_in[1];
    const float* b_offset = (const float*)d_in[2];
    const float* w_dcn    = (const float*)d_in[3];
    float* out = (float*)d_out;

    unsigned short* xT     = (unsigned short*)d_ws;                      // 16,777,216 B
    unsigned short* wt2    = (unsigned short*)((char*)d_ws + 16777216);  // 73,728 B
    unsigned short* wtoff2 = (unsigned short*)((char*)d_ws + 16850944);  // 36,864 B

    xpose_kernel<<<4096, 256, 0, stream>>>(x, xT);
    wcast_kernel<<<27, 256, 0, stream>>>(w_dcn, w_offset, wt2, wtoff2);
    fused_dcn_kernel<<<2048, 256, 0, stream>>>(xT, wtoff2, b_offset, wt2, out);
}